// Round 1
// baseline (1277.532 us; speedup 1.0000x reference)
//
#include <hip/hip_runtime.h>
#include <math.h>

#define B_ 128
#define L_ 50
#define D_ 128
#define S_ 12
#define HOPM1_ 1
#define NEG_INF_ -9e15f

// ---------------------------------------------------------------------------
// Local aggregator: 4-edge-type GAT over the session graph. One block per b.
// ---------------------------------------------------------------------------
__global__ __launch_bounds__(256) void local_agg_kernel(
    const int* __restrict__ inputs, const int* __restrict__ adj,
    const float* __restrict__ emb,
    const float* __restrict__ a0, const float* __restrict__ a1,
    const float* __restrict__ a2, const float* __restrict__ a3,
    float* __restrict__ hlocal_out)
{
  __shared__ float hs[L_][129];    // +1 pad: column reads hit distinct banks
  __shared__ float alds[4][129];
  __shared__ float att[L_][51];
  const int b = blockIdx.x, tid = threadIdx.x;

  if (tid < 128){
    alds[0][tid] = a0[tid]; alds[1][tid] = a1[tid];
    alds[2][tid] = a2[tid]; alds[3][tid] = a3[tid];
  }
  for (int i = tid; i < L_*D_; i += 256){
    int r = i >> 7, d = i & 127;
    hs[r][d] = emb[(size_t)inputs[b*L_ + r]*D_ + d];
  }
  __syncthreads();

  // logits[i][j] = leaky_relu( sum_d h_i*h_j*a_{adj-1} ), NEG_INF where adj==0
  for (int pth = tid; pth < L_*L_; pth += 256){
    int i = pth / L_, j = pth % L_;
    int at = adj[b*L_*L_ + pth];
    float lg = NEG_INF_;
    if (at >= 1 && at <= 4){
      const float* av = alds[at-1];
      float acc = 0.f;
      #pragma unroll 4
      for (int d = 0; d < D_; ++d) acc = fmaf(hs[i][d]*hs[j][d], av[d], acc);
      lg = acc >= 0.f ? acc : 0.2f*acc;
    }
    att[i][j] = lg;
  }
  __syncthreads();

  // row softmax (one thread per row; 50 rows)
  if (tid < L_){
    float m = -1e30f;
    for (int j = 0; j < L_; ++j) m = fmaxf(m, att[tid][j]);
    float sum = 0.f;
    for (int j = 0; j < L_; ++j){ float e = expf(att[tid][j]-m); att[tid][j] = e; sum += e; }
    float inv = 1.f/sum;
    for (int j = 0; j < L_; ++j) att[tid][j] *= inv;
  }
  __syncthreads();

  // h_local = attn @ h
  for (int i2 = tid; i2 < L_*D_; i2 += 256){
    int r = i2 >> 7, d = i2 & 127;
    float acc = 0.f;
    #pragma unroll 5
    for (int j = 0; j < L_; ++j) acc = fmaf(att[r][j], hs[j][d], acc);
    hlocal_out[(size_t)b*L_*D_ + i2] = acc;
  }
}

// ---------------------------------------------------------------------------
// Session mean: sum_item[b,:] = (emb[item] * mask).sum(1) / mask.sum
// ---------------------------------------------------------------------------
__global__ __launch_bounds__(128) void sum_item_kernel(
    const int* __restrict__ item, const int* __restrict__ mask,
    const float* __restrict__ emb, float* __restrict__ sum_it)
{
  const int b = blockIdx.x, d = threadIdx.x;
  float acc = 0.f, cnt = 0.f;
  for (int l = 0; l < L_; ++l){
    float mf = (float)mask[b*L_ + l];
    acc = fmaf(mf, emb[(size_t)item[b*L_+l]*D_ + d], acc);
    cnt += mf;
  }
  sum_it[b*D_ + d] = acc / cnt;
}

// ---------------------------------------------------------------------------
// Neighbor expansion: out_ids[t] = adj_all[src[t/S]][t%S], out_w likewise
// ---------------------------------------------------------------------------
__global__ void build_nbr_kernel(const int* __restrict__ src_ids, int n,
                                 const int* __restrict__ adj_all,
                                 const float* __restrict__ num_w,
                                 int* __restrict__ out_ids, float* __restrict__ out_w)
{
  int t = blockIdx.x*blockDim.x + threadIdx.x;
  if (t >= n) return;
  int parent = src_ids[t / S_];
  int s = t % S_;
  out_ids[t] = adj_all[(size_t)parent*S_ + s];
  out_w[t]   = num_w[(size_t)parent*S_ + s];
}

// ---------------------------------------------------------------------------
// GlobalAggregator pass. One 128-thread block handles G=4 (b,m) pairs so the
// gw1 (66KB) and gw3 (131KB) L2 reads amortize 4x. Stage-1 a-matrix staged in
// LDS transposed [k][s] (48B rows, 16B aligned -> broadcast ds_read_b128).
// ---------------------------------------------------------------------------
template<bool SV_IDS, bool NV_IDS>
__global__ __launch_bounds__(128) void gagg_kernel(
    const float* __restrict__ emb,
    const int*   __restrict__ sv_ids, const float* __restrict__ sv_vals,
    const int*   __restrict__ nv_ids, const float* __restrict__ nv_vals,
    const float* __restrict__ nw,     const float* __restrict__ sum_it,
    const float* __restrict__ gw1,    const float* __restrict__ gw2,
    const float* __restrict__ gw3,
    float* __restrict__ outp, int M)
{
  const int G = 4;
  __shared__ float a_t[G][129][12];   // a[s][k] transposed: [k][s]
  __shared__ float catl[G][256];      // concat(sv, nv_agg)
  __shared__ float scpart[2][G*S_];
  __shared__ float scores[G*S_];
  const int tid = threadIdx.x;        // 0..127, also the d / k index
  const int p0 = blockIdx.x * G;

  // ---- stage A: build a[s][k] = sum_item[k]*nv[s][k] (k<128), a[s][128]=nw[s]
  for (int g = 0; g < G; ++g){
    int p = p0 + g;
    int b = p / M;
    float sik = sum_it[b*D_ + tid];
    float v[12];
    #pragma unroll
    for (int s = 0; s < S_; ++s){
      float nvv = NV_IDS ? emb[(size_t)nv_ids[p*S_+s]*D_ + tid]
                         : nv_vals[((size_t)(p*S_+s))*D_ + tid];
      v[s] = sik * nvv;
    }
    float4* row = (float4*)(&a_t[g][tid][0]);
    row[0] = make_float4(v[0], v[1], v[2], v[3]);
    row[1] = make_float4(v[4], v[5], v[6], v[7]);
    row[2] = make_float4(v[8], v[9], v[10], v[11]);
    if (tid < S_) a_t[g][128][tid] = nw[p*S_ + tid];
  }
  __syncthreads();

  // ---- stage B: t[s][d] = lrelu(sum_k a[s][k]*gw1[k][d]); score = t . gw2
  float tacc[G][12];
  #pragma unroll
  for (int g = 0; g < G; ++g)
    #pragma unroll
    for (int s = 0; s < S_; ++s) tacc[g][s] = 0.f;

  for (int k = 0; k < 129; ++k){
    float gk = gw1[k*D_ + tid];
    #pragma unroll
    for (int g = 0; g < G; ++g){
      const float4* row = (const float4*)(&a_t[g][k][0]);
      float4 x = row[0], y = row[1], z = row[2];
      tacc[g][0]  = fmaf(x.x, gk, tacc[g][0]);
      tacc[g][1]  = fmaf(x.y, gk, tacc[g][1]);
      tacc[g][2]  = fmaf(x.z, gk, tacc[g][2]);
      tacc[g][3]  = fmaf(x.w, gk, tacc[g][3]);
      tacc[g][4]  = fmaf(y.x, gk, tacc[g][4]);
      tacc[g][5]  = fmaf(y.y, gk, tacc[g][5]);
      tacc[g][6]  = fmaf(y.z, gk, tacc[g][6]);
      tacc[g][7]  = fmaf(y.w, gk, tacc[g][7]);
      tacc[g][8]  = fmaf(z.x, gk, tacc[g][8]);
      tacc[g][9]  = fmaf(z.y, gk, tacc[g][9]);
      tacc[g][10] = fmaf(z.z, gk, tacc[g][10]);
      tacc[g][11] = fmaf(z.w, gk, tacc[g][11]);
    }
  }

  {
    float g2v = gw2[tid];
    int lane = tid & 63, wid = tid >> 6;
    #pragma unroll
    for (int g = 0; g < G; ++g){
      #pragma unroll
      for (int s = 0; s < S_; ++s){
        float tv = tacc[g][s];
        tv = tv >= 0.f ? tv : 0.2f*tv;     // leaky_relu(., 0.2)
        float vv = tv * g2v;
        vv += __shfl_xor(vv, 1);  vv += __shfl_xor(vv, 2);
        vv += __shfl_xor(vv, 4);  vv += __shfl_xor(vv, 8);
        vv += __shfl_xor(vv, 16); vv += __shfl_xor(vv, 32);
        if (lane == 0) scpart[wid][g*S_+s] = vv;
      }
    }
  }
  __syncthreads();
  if (tid < G*S_) scores[tid] = scpart[0][tid] + scpart[1][tid];
  __syncthreads();

  // ---- stage C: softmax over s, nv_agg, build concat in LDS
  for (int g = 0; g < G; ++g){
    int p = p0 + g;
    float sc[12]; float m = -1e30f;
    #pragma unroll
    for (int s = 0; s < S_; ++s){ sc[s] = scores[g*S_+s]; m = fmaxf(m, sc[s]); }
    float sum = 0.f;
    #pragma unroll
    for (int s = 0; s < S_; ++s){ sc[s] = expf(sc[s]-m); sum += sc[s]; }
    float inv = 1.f/sum;
    float agg = 0.f;
    #pragma unroll
    for (int s = 0; s < S_; ++s){
      float nvv = NV_IDS ? emb[(size_t)nv_ids[p*S_+s]*D_ + tid]
                         : nv_vals[((size_t)(p*S_+s))*D_ + tid];
      agg = fmaf(sc[s]*inv, nvv, agg);
    }
    float svv = SV_IDS ? emb[(size_t)sv_ids[p]*D_ + tid]
                       : sv_vals[(size_t)p*D_ + tid];
    catl[g][tid]      = svv;
    catl[g][D_ + tid] = agg;
  }
  __syncthreads();

  // ---- stage D: out = relu( concat @ gw3 )
  float o[G] = {0.f, 0.f, 0.f, 0.f};
  for (int k0 = 0; k0 < 2*D_; k0 += 4){
    float w0v = gw3[(k0+0)*D_ + tid];
    float w1v = gw3[(k0+1)*D_ + tid];
    float w2v = gw3[(k0+2)*D_ + tid];
    float w3v = gw3[(k0+3)*D_ + tid];
    #pragma unroll
    for (int g = 0; g < G; ++g){
      float4 c = *(const float4*)(&catl[g][k0]);
      o[g] = fmaf(c.x, w0v, o[g]);
      o[g] = fmaf(c.y, w1v, o[g]);
      o[g] = fmaf(c.z, w2v, o[g]);
      o[g] = fmaf(c.w, w3v, o[g]);
    }
  }
  #pragma unroll
  for (int g = 0; g < G; ++g)
    outp[(size_t)(p0+g)*D_ + tid] = fmaxf(o[g], 0.f);
}

// ---------------------------------------------------------------------------
// output = h_local (already in region0) + s_global (region1)
// ---------------------------------------------------------------------------
__global__ void final_add_kernel(float* __restrict__ dout){
  int i = blockIdx.x*blockDim.x + threadIdx.x;
  const int n4 = (B_*L_*D_)/4;
  if (i < n4){
    float4* o = (float4*)dout;
    const float4* s = (const float4*)(dout + B_*L_*D_);
    float4 a = o[i], b = s[i];
    a.x += b.x; a.y += b.y; a.z += b.z; a.w += b.w;
    o[i] = a;
  }
}

extern "C" void kernel_launch(void* const* d_in, const int* in_sizes, int n_in,
                              void* d_out, int out_size, void* d_ws, size_t ws_size,
                              hipStream_t stream)
{
  const int*   inputs  = (const int*)  d_in[0];
  const int*   adj     = (const int*)  d_in[1];
  const int*   mask    = (const int*)  d_in[2];
  const int*   item    = (const int*)  d_in[3];
  const float* emb     = (const float*)d_in[4];
  const int*   adj_all = (const int*)  d_in[5];
  const float* num_w   = (const float*)d_in[6];
  const float* a0      = (const float*)d_in[7];
  const float* a1      = (const float*)d_in[8];
  const float* a2      = (const float*)d_in[9];
  const float* a3      = (const float*)d_in[10];
  const float* gw1     = (const float*)d_in[11];  // [2][129][128]
  const float* gw2     = (const float*)d_in[12];  // [2][128]
  const float* gw3     = (const float*)d_in[13];  // [2][256][128]

  float* out     = (float*)d_out;
  float* hlocal  = out;                 // output region (starts as h_local)
  float* sglobal = out + B_*L_*D_;      // s_global region

  char* ws = (char*)d_ws;
  size_t off = 0;
  auto alloc = [&](size_t bytes)->char*{
    char* pp = ws + off; off += (bytes + 255) & ~(size_t)255; return pp;
  };
  float* sum_it = (float*)alloc((size_t)B_*D_*sizeof(float));
  int*   n1     = (int*)  alloc((size_t)B_*L_*S_*sizeof(int));          // [B,600]
  float* w0     = (float*)alloc((size_t)B_*L_*S_*sizeof(float));
  int*   n2     = (int*)  alloc((size_t)B_*L_*S_*S_*sizeof(int));       // [B,7200]
  float* w1     = (float*)alloc((size_t)B_*L_*S_*S_*sizeof(float));
  float* out0   = (float*)alloc((size_t)B_*L_*D_*sizeof(float));        // [B,50,128]
  float* out1   = (float*)alloc((size_t)B_*L_*S_*D_*sizeof(float));     // [B,600,128]

  local_agg_kernel<<<B_, 256, 0, stream>>>(inputs, adj, emb, a0, a1, a2, a3, hlocal);
  sum_item_kernel<<<B_, 128, 0, stream>>>(item, mask, emb, sum_it);
  build_nbr_kernel<<<(B_*L_*S_ + 255)/256, 256, 0, stream>>>(inputs, B_*L_*S_, adj_all, num_w, n1, w0);
  build_nbr_kernel<<<(B_*L_*S_*S_ + 255)/256, 256, 0, stream>>>(n1, B_*L_*S_*S_, adj_all, num_w, n2, w1);

  // n_hop=0, hp=0: sv=emb[inputs], nv=emb[n1]          -> out0 [B,50,D]
  gagg_kernel<true, true><<<(B_*L_)/4, 128, 0, stream>>>(
      emb, inputs, nullptr, n1, nullptr, w0, sum_it, gw1, gw2, gw3, out0, L_);
  // n_hop=0, hp=1: sv=emb[n1], nv=emb[n2]              -> out1 [B,600,D]
  gagg_kernel<true, true><<<(B_*L_*S_)/4, 128, 0, stream>>>(
      emb, n1, nullptr, n2, nullptr, w1, sum_it, gw1, gw2, gw3, out1, L_*S_);
  // n_hop=1, hp=0: sv=out0, nv=out1 (hop-1 weights)    -> s_global [B,50,D]
  gagg_kernel<false, false><<<(B_*L_)/4, 128, 0, stream>>>(
      emb, nullptr, out0, nullptr, out1, w0, sum_it,
      gw1 + 129*128, gw2 + 128, gw3 + 256*128, sglobal, L_);

  final_add_kernel<<<((B_*L_*D_/4) + 255)/256, 256, 0, stream>>>(out);
}

// Round 2
// 770.783 us; speedup vs baseline: 1.6574x; 1.6574x over previous
//
#include <hip/hip_runtime.h>
#include <math.h>

#define B_ 128
#define L_ 50
#define D_ 128
#define S_ 12
#define NEG_INF_ -9e15f

static __device__ __forceinline__ float4 ld4(const float* p){ return *(const float4*)p; }
static __device__ __forceinline__ float lrelu(float x){ return x >= 0.f ? x : 0.2f*x; }

// ---------------------------------------------------------------------------
// Local aggregator: 4-edge-type GAT over the session graph. One block per b.
// ---------------------------------------------------------------------------
__global__ __launch_bounds__(256) void local_agg_kernel(
    const int* __restrict__ inputs, const int* __restrict__ adj,
    const float* __restrict__ emb,
    const float* __restrict__ a0, const float* __restrict__ a1,
    const float* __restrict__ a2, const float* __restrict__ a3,
    float* __restrict__ hlocal_out)
{
  __shared__ float hs[L_][129];
  __shared__ float alds[4][129];
  __shared__ float att[L_][51];
  const int b = blockIdx.x, tid = threadIdx.x;

  if (tid < 128){
    alds[0][tid] = a0[tid]; alds[1][tid] = a1[tid];
    alds[2][tid] = a2[tid]; alds[3][tid] = a3[tid];
  }
  for (int i = tid; i < L_*D_; i += 256){
    int r = i >> 7, d = i & 127;
    hs[r][d] = emb[(size_t)inputs[b*L_ + r]*D_ + d];
  }
  __syncthreads();

  for (int pth = tid; pth < L_*L_; pth += 256){
    int i = pth / L_, j = pth % L_;
    int at = adj[b*L_*L_ + pth];
    float lg = NEG_INF_;
    if (at >= 1 && at <= 4){
      const float* av = alds[at-1];
      float acc = 0.f;
      #pragma unroll 4
      for (int d = 0; d < D_; ++d) acc = fmaf(hs[i][d]*hs[j][d], av[d], acc);
      lg = lrelu(acc);
    }
    att[i][j] = lg;
  }
  __syncthreads();

  if (tid < L_){
    float m = -1e30f;
    for (int j = 0; j < L_; ++j) m = fmaxf(m, att[tid][j]);
    float sum = 0.f;
    for (int j = 0; j < L_; ++j){ float e = expf(att[tid][j]-m); att[tid][j] = e; sum += e; }
    float inv = 1.f/sum;
    for (int j = 0; j < L_; ++j) att[tid][j] *= inv;
  }
  __syncthreads();

  for (int i2 = tid; i2 < L_*D_; i2 += 256){
    int r = i2 >> 7, d = i2 & 127;
    float acc = 0.f;
    #pragma unroll 5
    for (int j = 0; j < L_; ++j) acc = fmaf(att[r][j], hs[j][d], acc);
    hlocal_out[(size_t)b*L_*D_ + i2] = acc;
  }
}

// ---------------------------------------------------------------------------
// Session mean
// ---------------------------------------------------------------------------
__global__ __launch_bounds__(128) void sum_item_kernel(
    const int* __restrict__ item, const int* __restrict__ mask,
    const float* __restrict__ emb, float* __restrict__ sum_it)
{
  const int b = blockIdx.x, d = threadIdx.x;
  float acc = 0.f, cnt = 0.f;
  for (int l = 0; l < L_; ++l){
    float mf = (float)mask[b*L_ + l];
    acc = fmaf(mf, emb[(size_t)item[b*L_+l]*D_ + d], acc);
    cnt += mf;
  }
  sum_it[b*D_ + d] = acc / cnt;
}

// ---------------------------------------------------------------------------
// Neighbor expansion
// ---------------------------------------------------------------------------
__global__ void build_nbr_kernel(const int* __restrict__ src_ids, int n,
                                 const int* __restrict__ adj_all,
                                 const float* __restrict__ num_w,
                                 int* __restrict__ out_ids, float* __restrict__ out_w)
{
  int t = blockIdx.x*blockDim.x + threadIdx.x;
  if (t >= n) return;
  int parent = src_ids[t / S_];
  int s = t % S_;
  out_ids[t] = adj_all[(size_t)parent*S_ + s];
  out_w[t]   = num_w[(size_t)parent*S_ + s];
}

// ---------------------------------------------------------------------------
// GlobalAggregator pass, v2.
// Block = 128 threads (2 waves), G=4 (b,m) pairs per block.
// Thread (g = tid>>5, q = tid&31) owns pair g, d-columns 4q..4q+3.
// Per k: 3 broadcast ds_read_b128 (2 addrs/instr = free) + 1 gw1 float4 load
// feed 48 FMAs -> VALU-bound instead of LDS-issue-bound.
// catl unioned into a_t space: 24.8 KB LDS -> 6 blocks/CU -> 3 waves/SIMD.
// ---------------------------------------------------------------------------
template<bool SV_IDS, bool NV_IDS>
__global__ __launch_bounds__(128, 3) void gagg_kernel(
    const float* __restrict__ emb,
    const int*   __restrict__ sv_ids, const float* __restrict__ sv_vals,
    const int*   __restrict__ nv_ids, const float* __restrict__ nv_vals,
    const float* __restrict__ nw,     const float* __restrict__ sum_it,
    const float* __restrict__ gw1,    const float* __restrict__ gw2,
    const float* __restrict__ gw3,
    float* __restrict__ outp, int M)
{
  const int G = 4;
  // union: a_t[4][129][12] fp32 (24768 B) reused later as catl[4][256] (4096 B)
  __shared__ float smem[G*129*12];
  float* a_t  = smem;
  float* catl = smem;

  const int tid = threadIdx.x;
  const int g   = tid >> 5;          // pair within block (compute stages)
  const int q   = tid & 31;          // d-group: d = 4q..4q+3
  const int p0  = blockIdx.x * G;
  const int pg  = p0 + g;

  // ---- stage A: a[s][k] = sum_it[b][k]*nv[s][k] (k<128), a[s][128]=nw[s]
  {
    const int k = tid;               // 0..127 column
    for (int gg = 0; gg < G; ++gg){
      int p = p0 + gg;
      int b = p / M;
      float sik = sum_it[b*D_ + k];
      float v[S_];
      #pragma unroll
      for (int s = 0; s < S_; ++s){
        float nvv = NV_IDS ? emb[(size_t)nv_ids[p*S_+s]*D_ + k]
                           : nv_vals[((size_t)(p*S_+s))*D_ + k];
        v[s] = sik * nvv;
      }
      float* row = a_t + (gg*129 + k)*12;
      ((float4*)row)[0] = make_float4(v[0], v[1], v[2],  v[3]);
      ((float4*)row)[1] = make_float4(v[4], v[5], v[6],  v[7]);
      ((float4*)row)[2] = make_float4(v[8], v[9], v[10], v[11]);
    }
    if (tid < G*S_){
      int gg = tid / S_, s = tid % S_;
      a_t[(gg*129 + 128)*12 + s] = nw[(p0+gg)*S_ + s];
    }
  }
  __syncthreads();

  // ---- stage B: tacc[s][j] = sum_k a[s][k]*gw1[k][4q+j], rotated prefetch
  float tacc[S_][4];
  #pragma unroll
  for (int s = 0; s < S_; ++s)
    #pragma unroll
    for (int j = 0; j < 4; ++j) tacc[s][j] = 0.f;

  const float* arow = a_t + g*129*12;
  const float* gcol = gw1 + 4*q;

  float4 a0v = ((const float4*)arow)[0];
  float4 a1v = ((const float4*)arow)[1];
  float4 a2v = ((const float4*)arow)[2];
  float4 w4  = ld4(gcol);

  for (int k = 0; k < 129; ++k){
    float4 na0, na1, na2, nw4;
    if (k + 1 < 129){
      const float* r = arow + (k+1)*12;
      na0 = ((const float4*)r)[0];
      na1 = ((const float4*)r)[1];
      na2 = ((const float4*)r)[2];
      nw4 = ld4(gcol + (k+1)*D_);
    }
    float as[S_] = {a0v.x, a0v.y, a0v.z, a0v.w,
                    a1v.x, a1v.y, a1v.z, a1v.w,
                    a2v.x, a2v.y, a2v.z, a2v.w};
    #pragma unroll
    for (int s = 0; s < S_; ++s){
      tacc[s][0] = fmaf(as[s], w4.x, tacc[s][0]);
      tacc[s][1] = fmaf(as[s], w4.y, tacc[s][1]);
      tacc[s][2] = fmaf(as[s], w4.z, tacc[s][2]);
      tacc[s][3] = fmaf(as[s], w4.w, tacc[s][3]);
    }
    a0v = na0; a1v = na1; a2v = na2; w4 = nw4;
  }

  // ---- scores: score[s] = sum_d lrelu(t[s][d]) * gw2[d]; 32-lane butterfly
  float4 g2 = ld4(gw2 + 4*q);
  float score[S_];
  #pragma unroll
  for (int s = 0; s < S_; ++s){
    float v = lrelu(tacc[s][0])*g2.x + lrelu(tacc[s][1])*g2.y
            + lrelu(tacc[s][2])*g2.z + lrelu(tacc[s][3])*g2.w;
    v += __shfl_xor(v, 1);  v += __shfl_xor(v, 2);
    v += __shfl_xor(v, 4);  v += __shfl_xor(v, 8);
    v += __shfl_xor(v, 16);
    score[s] = v;                     // identical across the 32-lane group
  }

  // ---- stage C: softmax over s (redundant per lane), nv_agg for own 4 d
  float m = -1e30f;
  #pragma unroll
  for (int s = 0; s < S_; ++s) m = fmaxf(m, score[s]);
  float sum = 0.f;
  float ex[S_];
  #pragma unroll
  for (int s = 0; s < S_; ++s){ ex[s] = expf(score[s]-m); sum += ex[s]; }
  float inv = 1.f/sum;

  float4 agg = make_float4(0.f, 0.f, 0.f, 0.f);
  #pragma unroll
  for (int s = 0; s < S_; ++s){
    float4 nv4 = NV_IDS ? ld4(emb + (size_t)nv_ids[pg*S_+s]*D_ + 4*q)
                        : ld4(nv_vals + ((size_t)(pg*S_+s))*D_ + 4*q);
    float w = ex[s]*inv;
    agg.x = fmaf(w, nv4.x, agg.x);
    agg.y = fmaf(w, nv4.y, agg.y);
    agg.z = fmaf(w, nv4.z, agg.z);
    agg.w = fmaf(w, nv4.w, agg.w);
  }
  float4 sv4 = SV_IDS ? ld4(emb + (size_t)sv_ids[pg]*D_ + 4*q)
                      : ld4(sv_vals + (size_t)pg*D_ + 4*q);

  __syncthreads();                    // all a_t reads done; safe to overwrite
  *(float4*)(catl + g*256 + 4*q)        = sv4;
  *(float4*)(catl + g*256 + 128 + 4*q)  = agg;
  __syncthreads();

  // ---- stage D: out[d] = relu( sum_k catl[k]*gw3[k][d] ), d = 4q..4q+3
  float4 o = make_float4(0.f, 0.f, 0.f, 0.f);
  const float* cb = catl + g*256;
  const float* g3 = gw3 + 4*q;
  #pragma unroll 4
  for (int k0 = 0; k0 < 256; k0 += 4){
    float4 c  = ld4(cb + k0);
    float4 w0 = ld4(g3 + (size_t)(k0+0)*D_);
    float4 w1 = ld4(g3 + (size_t)(k0+1)*D_);
    float4 w2 = ld4(g3 + (size_t)(k0+2)*D_);
    float4 w3 = ld4(g3 + (size_t)(k0+3)*D_);
    o.x = fmaf(c.x, w0.x, o.x); o.x = fmaf(c.y, w1.x, o.x);
    o.x = fmaf(c.z, w2.x, o.x); o.x = fmaf(c.w, w3.x, o.x);
    o.y = fmaf(c.x, w0.y, o.y); o.y = fmaf(c.y, w1.y, o.y);
    o.y = fmaf(c.z, w2.y, o.y); o.y = fmaf(c.w, w3.y, o.y);
    o.z = fmaf(c.x, w0.z, o.z); o.z = fmaf(c.y, w1.z, o.z);
    o.z = fmaf(c.z, w2.z, o.z); o.z = fmaf(c.w, w3.z, o.z);
    o.w = fmaf(c.x, w0.w, o.w); o.w = fmaf(c.y, w1.w, o.w);
    o.w = fmaf(c.z, w2.w, o.w); o.w = fmaf(c.w, w3.w, o.w);
  }
  float4 st = make_float4(fmaxf(o.x,0.f), fmaxf(o.y,0.f),
                          fmaxf(o.z,0.f), fmaxf(o.w,0.f));
  *(float4*)(outp + (size_t)pg*D_ + 4*q) = st;
}

// ---------------------------------------------------------------------------
// output = h_local + s_global
// ---------------------------------------------------------------------------
__global__ void final_add_kernel(float* __restrict__ dout){
  int i = blockIdx.x*blockDim.x + threadIdx.x;
  const int n4 = (B_*L_*D_)/4;
  if (i < n4){
    float4* o = (float4*)dout;
    const float4* s = (const float4*)(dout + B_*L_*D_);
    float4 a = o[i], b = s[i];
    a.x += b.x; a.y += b.y; a.z += b.z; a.w += b.w;
    o[i] = a;
  }
}

extern "C" void kernel_launch(void* const* d_in, const int* in_sizes, int n_in,
                              void* d_out, int out_size, void* d_ws, size_t ws_size,
                              hipStream_t stream)
{
  const int*   inputs  = (const int*)  d_in[0];
  const int*   adj     = (const int*)  d_in[1];
  const int*   mask    = (const int*)  d_in[2];
  const int*   item    = (const int*)  d_in[3];
  const float* emb     = (const float*)d_in[4];
  const int*   adj_all = (const int*)  d_in[5];
  const float* num_w   = (const float*)d_in[6];
  const float* a0      = (const float*)d_in[7];
  const float* a1      = (const float*)d_in[8];
  const float* a2      = (const float*)d_in[9];
  const float* a3      = (const float*)d_in[10];
  const float* gw1     = (const float*)d_in[11];  // [2][129][128]
  const float* gw2     = (const float*)d_in[12];  // [2][128]
  const float* gw3     = (const float*)d_in[13];  // [2][256][128]

  float* out     = (float*)d_out;
  float* hlocal  = out;
  float* sglobal = out + B_*L_*D_;

  char* ws = (char*)d_ws;
  size_t off = 0;
  auto alloc = [&](size_t bytes)->char*{
    char* pp = ws + off; off += (bytes + 255) & ~(size_t)255; return pp;
  };
  float* sum_it = (float*)alloc((size_t)B_*D_*sizeof(float));
  int*   n1     = (int*)  alloc((size_t)B_*L_*S_*sizeof(int));
  float* w0     = (float*)alloc((size_t)B_*L_*S_*sizeof(float));
  int*   n2     = (int*)  alloc((size_t)B_*L_*S_*S_*sizeof(int));
  float* w1     = (float*)alloc((size_t)B_*L_*S_*S_*sizeof(float));
  float* out0   = (float*)alloc((size_t)B_*L_*D_*sizeof(float));
  float* out1   = (float*)alloc((size_t)B_*L_*S_*D_*sizeof(float));

  local_agg_kernel<<<B_, 256, 0, stream>>>(inputs, adj, emb, a0, a1, a2, a3, hlocal);
  sum_item_kernel<<<B_, 128, 0, stream>>>(item, mask, emb, sum_it);
  build_nbr_kernel<<<(B_*L_*S_ + 255)/256, 256, 0, stream>>>(inputs, B_*L_*S_, adj_all, num_w, n1, w0);
  build_nbr_kernel<<<(B_*L_*S_*S_ + 255)/256, 256, 0, stream>>>(n1, B_*L_*S_*S_, adj_all, num_w, n2, w1);

  gagg_kernel<true, true><<<(B_*L_)/4, 128, 0, stream>>>(
      emb, inputs, nullptr, n1, nullptr, w0, sum_it, gw1, gw2, gw3, out0, L_);
  gagg_kernel<true, true><<<(B_*L_*S_)/4, 128, 0, stream>>>(
      emb, n1, nullptr, n2, nullptr, w1, sum_it, gw1, gw2, gw3, out1, L_*S_);
  gagg_kernel<false, false><<<(B_*L_)/4, 128, 0, stream>>>(
      emb, nullptr, out0, nullptr, out1, w0, sum_it,
      gw1 + 129*128, gw2 + 128, gw3 + 256*128, sglobal, L_);

  final_add_kernel<<<((B_*L_*D_/4) + 255)/256, 256, 0, stream>>>(out);
}

// Round 3
// 751.208 us; speedup vs baseline: 1.7006x; 1.0261x over previous
//
#include <hip/hip_runtime.h>
#include <hip/hip_bf16.h>
#include <math.h>

#define B_ 128
#define L_ 50
#define D_ 128
#define S_ 12
#define NEG_INF_ -9e15f

typedef __attribute__((ext_vector_type(8))) short short8;
typedef __attribute__((ext_vector_type(4))) float f32x4;

static __device__ __forceinline__ float4 ld4(const float* p){ return *(const float4*)p; }
static __device__ __forceinline__ float2 ld2(const float* p){ return *(const float2*)p; }
static __device__ __forceinline__ float lrelu(float x){ return x >= 0.f ? x : 0.2f*x; }
static __device__ __forceinline__ short f2bf(float x){
  return __builtin_bit_cast(short, __float2bfloat16(x));   // RNE
}

// ---------------------------------------------------------------------------
// Local aggregator: 4-edge-type GAT over the session graph. One block per b.
// ---------------------------------------------------------------------------
__global__ __launch_bounds__(256) void local_agg_kernel(
    const int* __restrict__ inputs, const int* __restrict__ adj,
    const float* __restrict__ emb,
    const float* __restrict__ a0, const float* __restrict__ a1,
    const float* __restrict__ a2, const float* __restrict__ a3,
    float* __restrict__ hlocal_out)
{
  __shared__ float hs[L_][129];
  __shared__ float alds[4][129];
  __shared__ float att[L_][51];
  const int b = blockIdx.x, tid = threadIdx.x;

  if (tid < 128){
    alds[0][tid] = a0[tid]; alds[1][tid] = a1[tid];
    alds[2][tid] = a2[tid]; alds[3][tid] = a3[tid];
  }
  for (int i = tid; i < L_*D_; i += 256){
    int r = i >> 7, d = i & 127;
    hs[r][d] = emb[(size_t)inputs[b*L_ + r]*D_ + d];
  }
  __syncthreads();

  for (int pth = tid; pth < L_*L_; pth += 256){
    int i = pth / L_, j = pth % L_;
    int at = adj[b*L_*L_ + pth];
    float lg = NEG_INF_;
    if (at >= 1 && at <= 4){
      const float* av = alds[at-1];
      float acc = 0.f;
      #pragma unroll 4
      for (int d = 0; d < D_; ++d) acc = fmaf(hs[i][d]*hs[j][d], av[d], acc);
      lg = lrelu(acc);
    }
    att[i][j] = lg;
  }
  __syncthreads();

  if (tid < L_){
    float m = -1e30f;
    for (int j = 0; j < L_; ++j) m = fmaxf(m, att[tid][j]);
    float sum = 0.f;
    for (int j = 0; j < L_; ++j){ float e = expf(att[tid][j]-m); att[tid][j] = e; sum += e; }
    float inv = 1.f/sum;
    for (int j = 0; j < L_; ++j) att[tid][j] *= inv;
  }
  __syncthreads();

  for (int i2 = tid; i2 < L_*D_; i2 += 256){
    int r = i2 >> 7, d = i2 & 127;
    float acc = 0.f;
    #pragma unroll 5
    for (int j = 0; j < L_; ++j) acc = fmaf(att[r][j], hs[j][d], acc);
    hlocal_out[(size_t)b*L_*D_ + i2] = acc;
  }
}

// ---------------------------------------------------------------------------
// Session mean
// ---------------------------------------------------------------------------
__global__ __launch_bounds__(128) void sum_item_kernel(
    const int* __restrict__ item, const int* __restrict__ mask,
    const float* __restrict__ emb, float* __restrict__ sum_it)
{
  const int b = blockIdx.x, d = threadIdx.x;
  float acc = 0.f, cnt = 0.f;
  for (int l = 0; l < L_; ++l){
    float mf = (float)mask[b*L_ + l];
    acc = fmaf(mf, emb[(size_t)item[b*L_+l]*D_ + d], acc);
    cnt += mf;
  }
  sum_it[b*D_ + d] = acc / cnt;
}

// ---------------------------------------------------------------------------
// Neighbor expansion
// ---------------------------------------------------------------------------
__global__ void build_nbr_kernel(const int* __restrict__ src_ids, int n,
                                 const int* __restrict__ adj_all,
                                 const float* __restrict__ num_w,
                                 int* __restrict__ out_ids, float* __restrict__ out_w)
{
  int t = blockIdx.x*blockDim.x + threadIdx.x;
  if (t >= n) return;
  int parent = src_ids[t / S_];
  int s = t % S_;
  out_ids[t] = adj_all[(size_t)parent*S_ + s];
  out_w[t]   = num_w[(size_t)parent*S_ + s];
}

// ---------------------------------------------------------------------------
// Pack gw1[hop][k<128][d] into MFMA B-fragment order (bf16).
// Fragment (t,n): lane l, slot j  <-  gw1[k = t*32 + (l>>4)*8 + j][n*16 + (l&15)]
// (k-slot mapping is a consistent bijection shared with the A-frag build; the
//  MFMA K-reduction is permutation-invariant so only consistency matters.)
// ---------------------------------------------------------------------------
__global__ void prep_gw1frag_kernel(const float* __restrict__ gw1, short* __restrict__ outf){
  int idx = blockIdx.x*256 + threadIdx.x;     // 0..2047 = t(4) x n(8) x lane(64)
  int hop = blockIdx.y;
  int lane = idx & 63, n = (idx >> 6) & 7, t = idx >> 9;
  int g4 = lane >> 4, col = lane & 15;
  const float* g1 = gw1 + (size_t)hop*129*128;
  size_t base = (size_t)hop*16384 + ((size_t)(t*8 + n)*64 + lane)*8;
  #pragma unroll
  for (int j = 0; j < 8; ++j){
    int k = t*32 + g4*8 + j;
    outf[base + j] = f2bf(g1[(size_t)k*128 + n*16 + col]);
  }
}

// ---------------------------------------------------------------------------
// GlobalAggregator, MFMA version.
// Block = 256 thr = 4 waves; each wave owns NP=8 pairs sequentially.
// Stage B: per pair a[s][k]=si[k]*nv[s][k] -> A-frags from direct emb gathers
// (bf16), B = gw1 frags resident in 128 VGPRs, 32x mfma_16x16x32 -> t[s][d].
// nw rank-1 term added fp32 before leaky-relu (keeps bf16 error tiny).
// C/D frag layout (verified): col=lane&15, row=(lane>>4)*4+reg.
// Scores -> softmax (redundant/lane) -> stage C gathers (fp32, L2-hot) ->
// catl in wave-private LDS -> stage D split-k fp32 VALU.
// ---------------------------------------------------------------------------
template<bool SV_IDS, bool NV_IDS>
__global__ __launch_bounds__(256, 2) void gagg_mfma_kernel(
    const float* __restrict__ emb,
    const int*   __restrict__ sv_ids, const float* __restrict__ sv_vals,
    const int*   __restrict__ nv_ids, const float* __restrict__ nv_vals,
    const float* __restrict__ nw,     const float* __restrict__ sum_it,
    const short* __restrict__ gw1f,   const float* __restrict__ gw1_last,
    const float* __restrict__ gw2,    const float* __restrict__ gw3,
    float* __restrict__ outp, int M)
{
  const int NP = 8;
  __shared__ float catl[4][256];
  const int tid  = threadIdx.x;
  const int wid  = tid >> 6;
  const int lane = tid & 63;
  const int g4   = lane >> 4;
  const int col  = lane & 15;

  // B fragments resident in VGPRs for the whole block
  short8 bfr[4][8];
  {
    const short8* fp = (const short8*)gw1f;
    #pragma unroll
    for (int t = 0; t < 4; ++t)
      #pragma unroll
      for (int n = 0; n < 8; ++n)
        bfr[t][n] = fp[(t*8 + n)*64 + lane];
  }
  // hoisted per-lane weight columns (same across pairs)
  float g2v[8], glv[8];
  #pragma unroll
  for (int n = 0; n < 8; ++n){
    g2v[n] = gw2[n*16 + col];
    glv[n] = gw1_last[n*16 + col];
  }

  const int pbase = blockIdx.x * (4*NP) + wid*NP;

  for (int np = 0; np < NP; ++np){
    const int p = pbase + np;              // grid sized so p is always valid
    const int b = p / M;

    // ---------- stage B: A-frag build + MFMA ----------
    const int   srow  = col;               // A row = s (12..15 masked)
    const int   sc_   = srow < S_ ? srow : 0;
    const float* nvrow = NV_IDS
        ? emb + (size_t)nv_ids[p*S_ + sc_] * D_
        : nv_vals + ((size_t)p*S_ + sc_) * D_;
    const float* sib = sum_it + b*D_;

    f32x4 acc[8];
    #pragma unroll
    for (int n = 0; n < 8; ++n) acc[n] = (f32x4){0.f,0.f,0.f,0.f};

    #pragma unroll
    for (int t = 0; t < 4; ++t){
      short8 af = (short8){0,0,0,0,0,0,0,0};
      if (srow < S_){                      // exec-masked: no gather for pad rows
        const int k0 = t*32 + g4*8;
        float4 s0 = ld4(sib + k0), s1 = ld4(sib + k0 + 4);
        float4 v0 = ld4(nvrow + k0), v1 = ld4(nvrow + k0 + 4);
        af[0] = f2bf(s0.x * v0.x);
        af[1] = f2bf(s0.y * v0.y);
        af[2] = f2bf(s0.z * v0.z);
        af[3] = f2bf(s0.w * v0.w);
        af[4] = f2bf(s1.x * v1.x);
        af[5] = f2bf(s1.y * v1.y);
        af[6] = f2bf(s1.z * v1.z);
        af[7] = f2bf(s1.w * v1.w);
      }
      #pragma unroll
      for (int n = 0; n < 8; ++n)
        acc[n] = __builtin_amdgcn_mfma_f32_16x16x32_bf16(af, bfr[t][n], acc[n], 0, 0, 0);
    }

    // ---------- nw rank-1 (fp32) + scores ----------
    float nwv[4];
    #pragma unroll
    for (int r = 0; r < 4; ++r){
      int s = g4*4 + r;
      nwv[r] = nw[p*S_ + (s < S_ ? s : 0)];
    }
    float sc4[4];
    #pragma unroll
    for (int r = 0; r < 4; ++r){
      float pr = 0.f;
      #pragma unroll
      for (int n = 0; n < 8; ++n){
        float tv = acc[n][r] + nwv[r]*glv[n];     // t[s][d] incl. nw column
        pr = fmaf(lrelu(tv), g2v[n], pr);
      }
      pr += __shfl_xor(pr, 1); pr += __shfl_xor(pr, 2);
      pr += __shfl_xor(pr, 4); pr += __shfl_xor(pr, 8);
      sc4[r] = pr;                          // score[s=4*g4+r], replicated /16
    }
    float w[S_];
    {
      float ss[S_];
      #pragma unroll
      for (int grp = 0; grp < 3; ++grp)     // s = 0..11 lives in groups 0..2
        #pragma unroll
        for (int r = 0; r < 4; ++r)
          ss[grp*4 + r] = __shfl(sc4[r], grp*16);
      float m = -1e30f;
      #pragma unroll
      for (int s = 0; s < S_; ++s) m = fmaxf(m, ss[s]);
      float sum = 0.f;
      #pragma unroll
      for (int s = 0; s < S_; ++s){ ss[s] = expf(ss[s]-m); sum += ss[s]; }
      float inv = 1.f/sum;
      #pragma unroll
      for (int s = 0; s < S_; ++s) w[s] = ss[s]*inv;
    }

    // ---------- stage C: attn-weighted nv + sv (fp32, rows L2-hot) ----------
    float2 agg = {0.f, 0.f};
    #pragma unroll
    for (int s = 0; s < S_; ++s){
      const float* row = NV_IDS ? emb + (size_t)nv_ids[p*S_+s]*D_
                                : nv_vals + ((size_t)p*S_+s)*D_;
      float2 v = ld2(row + 2*lane);
      agg.x = fmaf(w[s], v.x, agg.x);
      agg.y = fmaf(w[s], v.y, agg.y);
    }
    const float* svrow = SV_IDS ? emb + (size_t)sv_ids[p]*D_
                                : sv_vals + (size_t)p*D_;
    float2 sv2 = ld2(svrow + 2*lane);

    *(float2*)&catl[wid][2*lane]      = sv2;
    *(float2*)&catl[wid][D_ + 2*lane] = agg;
    asm volatile("s_waitcnt lgkmcnt(0)" ::: "memory");
    __builtin_amdgcn_sched_barrier(0);

    // ---------- stage D: out = relu(catl @ gw3), split-k over half-waves ----
    const int half = lane >> 5, dq = lane & 31;
    const float* g3 = gw3 + (size_t)(half*128)*D_ + 4*dq;
    const float* cb = &catl[wid][half*128];
    float4 o = {0.f,0.f,0.f,0.f};
    #pragma unroll 4
    for (int k0 = 0; k0 < 128; k0 += 4){
      float4 c  = *(const float4*)(cb + k0);
      float4 ga = ld4(g3 + (size_t)(k0+0)*D_);
      float4 gb = ld4(g3 + (size_t)(k0+1)*D_);
      float4 gc = ld4(g3 + (size_t)(k0+2)*D_);
      float4 gd = ld4(g3 + (size_t)(k0+3)*D_);
      o.x = fmaf(c.x, ga.x, o.x); o.y = fmaf(c.x, ga.y, o.y);
      o.z = fmaf(c.x, ga.z, o.z); o.w = fmaf(c.x, ga.w, o.w);
      o.x = fmaf(c.y, gb.x, o.x); o.y = fmaf(c.y, gb.y, o.y);
      o.z = fmaf(c.y, gb.z, o.z); o.w = fmaf(c.y, gb.w, o.w);
      o.x = fmaf(c.z, gc.x, o.x); o.y = fmaf(c.z, gc.y, o.y);
      o.z = fmaf(c.z, gc.z, o.z); o.w = fmaf(c.z, gc.w, o.w);
      o.x = fmaf(c.w, gd.x, o.x); o.y = fmaf(c.w, gd.y, o.y);
      o.z = fmaf(c.w, gd.z, o.z); o.w = fmaf(c.w, gd.w, o.w);
    }
    o.x += __shfl_xor(o.x, 32); o.y += __shfl_xor(o.y, 32);
    o.z += __shfl_xor(o.z, 32); o.w += __shfl_xor(o.w, 32);
    if (half == 0){
      float4 st = {fmaxf(o.x,0.f), fmaxf(o.y,0.f), fmaxf(o.z,0.f), fmaxf(o.w,0.f)};
      *(float4*)(outp + (size_t)p*D_ + 4*dq) = st;
    }
    // drain this pair's catl reads before next pair overwrites catl[wid]
    asm volatile("s_waitcnt lgkmcnt(0)" ::: "memory");
    __builtin_amdgcn_sched_barrier(0);
  }
}

// ---------------------------------------------------------------------------
// output = h_local + s_global
// ---------------------------------------------------------------------------
__global__ void final_add_kernel(float* __restrict__ dout){
  int i = blockIdx.x*blockDim.x + threadIdx.x;
  const int n4 = (B_*L_*D_)/4;
  if (i < n4){
    float4* o = (float4*)dout;
    const float4* s = (const float4*)(dout + B_*L_*D_);
    float4 a = o[i], b = s[i];
    a.x += b.x; a.y += b.y; a.z += b.z; a.w += b.w;
    o[i] = a;
  }
}

extern "C" void kernel_launch(void* const* d_in, const int* in_sizes, int n_in,
                              void* d_out, int out_size, void* d_ws, size_t ws_size,
                              hipStream_t stream)
{
  const int*   inputs  = (const int*)  d_in[0];
  const int*   adj     = (const int*)  d_in[1];
  const int*   mask    = (const int*)  d_in[2];
  const int*   item    = (const int*)  d_in[3];
  const float* emb     = (const float*)d_in[4];
  const int*   adj_all = (const int*)  d_in[5];
  const float* num_w   = (const float*)d_in[6];
  const float* a0      = (const float*)d_in[7];
  const float* a1      = (const float*)d_in[8];
  const float* a2      = (const float*)d_in[9];
  const float* a3      = (const float*)d_in[10];
  const float* gw1     = (const float*)d_in[11];  // [2][129][128]
  const float* gw2     = (const float*)d_in[12];  // [2][128]
  const float* gw3     = (const float*)d_in[13];  // [2][256][128]

  float* out     = (float*)d_out;
  float* hlocal  = out;
  float* sglobal = out + B_*L_*D_;

  char* ws = (char*)d_ws;
  size_t off = 0;
  auto alloc = [&](size_t bytes)->char*{
    char* pp = ws + off; off += (bytes + 255) & ~(size_t)255; return pp;
  };
  float* sum_it = (float*)alloc((size_t)B_*D_*sizeof(float));
  int*   n1     = (int*)  alloc((size_t)B_*L_*S_*sizeof(int));
  float* w0     = (float*)alloc((size_t)B_*L_*S_*sizeof(float));
  int*   n2     = (int*)  alloc((size_t)B_*L_*S_*S_*sizeof(int));
  float* w1     = (float*)alloc((size_t)B_*L_*S_*S_*sizeof(float));
  float* out0   = (float*)alloc((size_t)B_*L_*D_*sizeof(float));
  float* out1   = (float*)alloc((size_t)B_*L_*S_*D_*sizeof(float));
  short* gw1f   = (short*)alloc((size_t)2*16384*sizeof(short));   // B-frags, both hops

  prep_gw1frag_kernel<<<dim3(8,2), 256, 0, stream>>>(gw1, gw1f);
  local_agg_kernel<<<B_, 256, 0, stream>>>(inputs, adj, emb, a0, a1, a2, a3, hlocal);
  sum_item_kernel<<<B_, 128, 0, stream>>>(item, mask, emb, sum_it);
  build_nbr_kernel<<<(B_*L_*S_ + 255)/256, 256, 0, stream>>>(inputs, B_*L_*S_, adj_all, num_w, n1, w0);
  build_nbr_kernel<<<(B_*L_*S_*S_ + 255)/256, 256, 0, stream>>>(n1, B_*L_*S_*S_, adj_all, num_w, n2, w1);

  // hop0, hp=0: sv=emb[inputs], nv=emb[n1]          -> out0 [6400,128]
  gagg_mfma_kernel<true,true><<<(B_*L_)/32, 256, 0, stream>>>(
      emb, inputs, nullptr, n1, nullptr, w0, sum_it,
      gw1f, gw1 + 128*128, gw2, gw3, out0, L_);
  // hop0, hp=1: sv=emb[n1], nv=emb[n2]              -> out1 [76800,128]
  gagg_mfma_kernel<true,true><<<(B_*L_*S_)/32, 256, 0, stream>>>(
      emb, n1, nullptr, n2, nullptr, w1, sum_it,
      gw1f, gw1 + 128*128, gw2, gw3, out1, L_*S_);
  // hop1, hp=0: sv=out0, nv=out1 (hop-0 weights)    -> s_global [6400,128]
  gagg_mfma_kernel<false,false><<<(B_*L_)/32, 256, 0, stream>>>(
      emb, nullptr, out0, nullptr, out1, w0, sum_it,
      gw1f + 16384, gw1 + 129*128 + 128*128, gw2 + 128, gw3 + 256*128,
      sglobal, L_);

  final_add_kernel<<<((B_*L_*D_/4) + 255)/256, 256, 0, stream>>>(out);
}